// Round 1
// baseline (52.652 us; speedup 1.0000x reference)
//
#include <hip/hip_runtime.h>
#include <hip/hip_bf16.h>

typedef unsigned short u16;
typedef unsigned int u32;
typedef __attribute__((ext_vector_type(8))) short bf16x8;
typedef __attribute__((ext_vector_type(4))) float f32x4;

__device__ __forceinline__ u16 f2bf(float f) {
  return __builtin_bit_cast(u16, __float2bfloat16(f));
}

__device__ __forceinline__ bf16x8 ld_frag16(const u16* p) {
  return __builtin_bit_cast(bf16x8, *reinterpret_cast<const uint4*>(p));
}

__device__ __forceinline__ void gload_lds16(const void* g, void* l) {
  __builtin_amdgcn_global_load_lds((const __attribute__((address_space(1))) void*)g,
                                   (__attribute__((address_space(3))) void*)l, 16, 0, 0);
}

// ---------------------------------------------------------------------------
// Kernel 1: Y[b] = bf16( W @ X[b] )   W:[256][256] f32, X:[256][1024] f32
// Y stored bf16 row-major [b][256][1024] in d_ws.
// BM=128, BN=64, BK=32, 4 waves (2x2), frags 4x2 of 16x16x32.
// ---------------------------------------------------------------------------
__global__ __launch_bounds__(256, 3) void gemm1(
    const float* __restrict__ x, const float* __restrict__ weight,
    u16* __restrict__ Y)
{
  constexpr int Nn = 1024, K = 256, BK = 32, SB = 40;
  __shared__ __align__(16) u16 As[128 * 32];   // [r][k], 16B chunks XOR-swizzled
  __shared__ __align__(16) u16 Bs[64 * SB];    // [n][k], row stride 40

  const int t = threadIdx.x;
  const int b = blockIdx.z, mt = blockIdx.y, n0 = blockIdx.x * 64;

  const float* Wp = weight + (size_t)mt * 128 * K;
  const float* Xb = x + (size_t)b * K * Nn;

  const int w = t >> 6, l = t & 63;
  const int wm = w >> 1, wn = w & 1;
  const int lr = l & 15, lg = l >> 4;

  // A-staging map: thread t -> row ar (0..127), col base akc (0 or 16)
  const int ar = t >> 1, akc = (t & 1) * 16;
  // B-staging map: col bm (0..63), k-quad bkq (0..3)
  const int bm = t & 63, bkq = t >> 6;
  const float* Xcol = Xb + n0 + bm;

  f32x4 acc[4][2] = {};

  for (int kt = 0; kt < K / BK; ++kt) {
    const int k0 = kt * BK;

    // ---- stage A: W fp32 -> bf16, swizzled chunk placement ----
    float4 a4[4];
#pragma unroll
    for (int uu = 0; uu < 4; ++uu)
      a4[uu] = reinterpret_cast<const float4*>(Wp + (size_t)ar * K + k0 + akc)[uu];
    union { uint4 q[2]; u16 s[16]; } ua;
#pragma unroll
    for (int uu = 0; uu < 4; ++uu) {
      ua.s[uu * 4 + 0] = f2bf(a4[uu].x); ua.s[uu * 4 + 1] = f2bf(a4[uu].y);
      ua.s[uu * 4 + 2] = f2bf(a4[uu].z); ua.s[uu * 4 + 3] = f2bf(a4[uu].w);
    }
    {
      const int c0 = akc >> 3;              // 0 or 2
      const int sw = (ar >> 1) & 3;
      uint4* Aq = reinterpret_cast<uint4*>(As);
      Aq[ar * 4 + ((c0 + 0) ^ sw)] = ua.q[0];
      Aq[ar * 4 + ((c0 + 1) ^ sw)] = ua.q[1];
    }

    // ---- stage B: X fp32 -> bf16 transposed [n][k] ----
    float v[8];
#pragma unroll
    for (int j = 0; j < 8; ++j)
      v[j] = Xcol[(size_t)(k0 + bkq * 8 + j) * Nn];
    union { uint4 q; u16 s[8]; } ub;
#pragma unroll
    for (int j = 0; j < 8; ++j) ub.s[j] = f2bf(v[j]);
    reinterpret_cast<uint4*>(Bs)[bm * 5 + bkq] = ub.q;   // elem off bm*40+bkq*8

    __syncthreads();

    // ---- fragments + MFMA ----
    bf16x8 af[4], bfr[2];
#pragma unroll
    for (int mi = 0; mi < 4; ++mi) {
      const int rr = wm * 64 + mi * 16 + lr;
      const int cw = lg ^ ((rr >> 1) & 3);
      af[mi] = ld_frag16(As + rr * BK + cw * 8);
    }
#pragma unroll
    for (int ni = 0; ni < 2; ++ni) {
      const int cc = wn * 32 + ni * 16 + lr;
      bfr[ni] = ld_frag16(Bs + cc * SB + lg * 8);
    }
#pragma unroll
    for (int mi = 0; mi < 4; ++mi)
#pragma unroll
      for (int ni = 0; ni < 2; ++ni)
        acc[mi][ni] = __builtin_amdgcn_mfma_f32_16x16x32_bf16(
            af[mi], bfr[ni], acc[mi][ni], 0, 0, 0);

    __syncthreads();
  }

  // ---- epilogue: store bf16 Y ----
#pragma unroll
  for (int mi = 0; mi < 4; ++mi) {
#pragma unroll
    for (int rr = 0; rr < 4; ++rr) {
      const int row = mt * 128 + wm * 64 + mi * 16 + lg * 4 + rr;
      u16* Yrow = Y + ((size_t)(b * 256 + row)) * Nn + n0;
#pragma unroll
      for (int ni = 0; ni < 2; ++ni) {
        const int col = wn * 32 + ni * 16 + lr;
        Yrow[col] = f2bf(acc[mi][ni][rr]);
      }
    }
  }
}

// ---------------------------------------------------------------------------
// Kernel 2: out[b][h*128+i][m] = relu( sum_k Y[b][h*128+i][k]*adj_h[b][k][m] + bias )
// BM=128 (full half), BN=64, BK=32. Grid (16 n-tiles, 2 halves, 16 batches).
// ---------------------------------------------------------------------------
__global__ __launch_bounds__(256, 3) void gemm2(
    const float* __restrict__ adj1, const float* __restrict__ adj2,
    const u16* __restrict__ Y, const float* __restrict__ bias,
    float* __restrict__ out)
{
  constexpr int Nn = 1024, BK = 32, SB = 40;
  __shared__ __align__(16) u16 As[128 * 32];
  __shared__ __align__(16) u16 Bs[64 * SB];

  const int t = threadIdx.x;
  const int b = blockIdx.z, h = blockIdx.y, n0 = blockIdx.x * 64;

  const float* adj = (h == 0 ? adj1 : adj2) + (size_t)b * Nn * Nn;
  const u16* Yb = Y + ((size_t)(b * 256 + h * 128)) * Nn;  // [128][1024] bf16

  const int w = t >> 6, l = t & 63;
  const int wm = w >> 1, wn = w & 1;
  const int lr = l & 15, lg = l >> 4;

  const int bm = t & 63, bkq = t >> 6;
  const float* adjcol = adj + n0 + bm;

  f32x4 acc[4][2] = {};

  for (int kt = 0; kt < Nn / BK; ++kt) {
    const int k0 = kt * BK;

    // ---- stage A (Y bf16) via global_load_lds, source-chunk swizzled ----
#pragma unroll
    for (int j = 0; j < 2; ++j) {
      const int chunkbase = j * 256 + w * 64;        // lane adds l
      const int chunk = chunkbase + l;
      const int r = chunk >> 2, c = chunk & 3;
      const int cg = c ^ ((r >> 1) & 3);
      gload_lds16(Yb + (size_t)r * Nn + k0 + cg * 8,
                  (void*)(As + chunkbase * 8));
    }

    // ---- stage B: adj fp32 -> bf16 transposed [n][k] ----
    float v[8];
#pragma unroll
    for (int j = 0; j < 8; ++j)
      v[j] = adjcol[(size_t)(k0 + bkq * 8 + j) * Nn];
    union { uint4 q; u16 s[8]; } ub;
#pragma unroll
    for (int j = 0; j < 8; ++j) ub.s[j] = f2bf(v[j]);
    reinterpret_cast<uint4*>(Bs)[bm * 5 + bkq] = ub.q;

    __syncthreads();

    // ---- fragments + MFMA ----
    bf16x8 af[4], bfr[2];
#pragma unroll
    for (int mi = 0; mi < 4; ++mi) {
      const int rr = wm * 64 + mi * 16 + lr;
      const int cw = lg ^ ((rr >> 1) & 3);
      af[mi] = ld_frag16(As + rr * BK + cw * 8);
    }
#pragma unroll
    for (int ni = 0; ni < 2; ++ni) {
      const int cc = wn * 32 + ni * 16 + lr;
      bfr[ni] = ld_frag16(Bs + cc * SB + lg * 8);
    }
#pragma unroll
    for (int mi = 0; mi < 4; ++mi)
#pragma unroll
      for (int ni = 0; ni < 2; ++ni)
        acc[mi][ni] = __builtin_amdgcn_mfma_f32_16x16x32_bf16(
            af[mi], bfr[ni], acc[mi][ni], 0, 0, 0);

    __syncthreads();
  }

  // ---- epilogue: bias + relu, fp32 store ----
#pragma unroll
  for (int mi = 0; mi < 4; ++mi) {
#pragma unroll
    for (int rr = 0; rr < 4; ++rr) {
      const int go = h * 128 + wm * 64 + mi * 16 + lg * 4 + rr;
      const float bi = bias[go];
      float* orow = out + ((size_t)(b * 256 + go)) * Nn + n0;
#pragma unroll
      for (int ni = 0; ni < 2; ++ni) {
        const int col = wn * 32 + ni * 16 + lr;
        orow[col] = fmaxf(acc[mi][ni][rr] + bi, 0.f);
      }
    }
  }
}

extern "C" void kernel_launch(void* const* d_in, const int* in_sizes, int n_in,
                              void* d_out, int out_size, void* d_ws, size_t ws_size,
                              hipStream_t stream) {
  const float* x    = (const float*)d_in[0];
  const float* adj1 = (const float*)d_in[1];
  const float* adj2 = (const float*)d_in[2];
  const float* wgt  = (const float*)d_in[3];
  const float* bias = (const float*)d_in[4];
  float* out = (float*)d_out;
  u16* Y = (u16*)d_ws;   // 16*256*1024 bf16 = 8.4 MB

  dim3 blk(256);
  dim3 g1(16, 2, 16);   // n-tiles, m-tiles(2x128), batch
  gemm1<<<g1, blk, 0, stream>>>(x, wgt, Y);
  dim3 g2(16, 2, 16);   // n-tiles, half, batch
  gemm2<<<g2, blk, 0, stream>>>(adj1, adj2, Y, bias, out);
}